// Round 19
// baseline (155.722 us; speedup 1.0000x reference)
//
#include <hip/hip_runtime.h>
#include <stdint.h>

#define BTOT 512
#define SQLEN 512
#define TTAB 20
#define EMB 32
#define DDIM 322            // E*10+2
#define KP 352              // padded K in wb2 layout (11*32)
#define NP 384              // padded N (24*16) -> 6 frags per wave, 4 waves
#define MBLK 64             // rows per block
#define LDA 360             // A_lds row stride in bf16 elems (720B)
#define NFRAG 24            // total 16-wide N fragments

typedef __attribute__((ext_vector_type(4))) float f32x4;
typedef __attribute__((ext_vector_type(8))) __bf16 bf16x8;

static __device__ __forceinline__ unsigned short f2bf(float f) {
    unsigned int u = __float_as_uint(f);
    u += 0x7fffu + ((u >> 16) & 1u);   // round-to-nearest-even
    return (unsigned short)(u >> 16);
}

// hardware RNE cvt pair-pack (v_cvt_pk_bf16_f32)
static __device__ __forceinline__ unsigned int pk2(float x, float y) {
    __bf16 a = (__bf16)x, b = (__bf16)y;
    unsigned short ua = __builtin_bit_cast(unsigned short, a);
    unsigned short ub = __builtin_bit_cast(unsigned short, b);
    return (unsigned int)ua | ((unsigned int)ub << 16);
}

// W [322][322] f32 (o x d) -> wb2 bf16 fragments in MFMA lane order.
// (n,k) -> frag ((k>>5)*24 + (n>>4)), lane ((n&15) | (((k>>3)&3)<<4)), e (k&7)
// A wave's B-fragment load = wb2 + frag*512 + lane*8 : contiguous 1KB.
__global__ void prep_w(const float* __restrict__ W, unsigned short* __restrict__ wb2) {
    int idx = blockIdx.x * 256 + threadIdx.x;
    if (idx >= NP * KP) return;
    int n = idx / KP;
    int k = idx - n * KP;
    float v = (n < DDIM && k < DDIM) ? W[n * DDIM + k] : 0.0f;
    int dst = ((k >> 5) * NFRAG + (n >> 4)) * 512
            + ((n & 15) + (((k >> 3) & 3) << 4)) * 8 + (k & 7);
    wb2[dst] = f2bf(v);
}

__global__ __launch_bounds__(256, 3) void fused_embed_gemm(
    const float* __restrict__ feature,       // [BT*SQ][12]
    const float* __restrict__ join_tables,   // [BT][20][32]
    const float* __restrict__ type_embed,    // [32][32]
    const float* __restrict__ column_embed,  // [300][32]
    const unsigned short* __restrict__ wb2,  // permuted bf16 W fragments
    const float* __restrict__ W,             // original W for cost columns
    const float* __restrict__ bias,          // [322]
    float* __restrict__ out)                 // [BT*SQ][322] f32
{
    __shared__ __align__(16) unsigned short A_lds[MBLK * LDA];  // 45 KB (reused by epilogue)
    __shared__ float F_lds[MBLK * 12];                          // 3 KB

    const int t = threadIdx.x;
    const long mbase = (long)blockIdx.x * MBLK;
    const int b = (int)(mbase >> 9);   // 64 | 512 => whole block in one batch

    const int lane = t & 63;
    const int wn   = t >> 6;          // wave owns frags wn*6 .. wn*6+5
    const int l15  = lane & 15;
    const int lq   = lane >> 4;
    const unsigned short* bbase = wb2 + ((long)(wn * 6) * 512) + lane * 8;

    bf16x8 b0[6], b1[6];

#define LOAD_B(bank, ksl)                                                        \
    _Pragma("unroll")                                                            \
    for (int nf = 0; nf < 6; ++nf)                                               \
        bank[nf] = *reinterpret_cast<const bf16x8*>(bbase + (long)((ksl) * NFRAG + nf) * 512);

    // ---- stage the 64 feature rows ----
    {
        const float* src = feature + mbase * 12;
        #pragma unroll
        for (int i = 0; i < 3; ++i) {
            int off = i * 256 + t;
            F_lds[off] = src[off];
        }
    }
    __syncthreads();

    // ---- gather embeddings into A_lds as bf16, float4 per iter (k < 320 only) ----
    const float* jtb = join_tables + (long)b * (TTAB * EMB);
    #pragma unroll 4
    for (int i = 0; i < 20; ++i) {              // 64 rows * 80 quads / 256 thr
        int pidx = i * 256 + t;
        int row = pidx / 80;
        int q = pidx - row * 80;
        int d = q << 2;
        int c = q >> 3;
        int j = d & 31;
        float4 v = make_float4(0.f, 0.f, 0.f, 0.f);
        int id = (int)F_lds[row * 12 + c];
        const float* src;
        bool nz = true;
        if (c == 0)                            { src = type_embed + id * EMB;  nz = (id != 0); }
        else if (c == 1 || (c >= 4 && c <= 6)) { src = jtb + id * EMB; }
        else                                   { src = column_embed + id * EMB; nz = (id != 0); }
        if (nz) v = *reinterpret_cast<const float4*>(src + j);
        uint2 pk;
        pk.x = pk2(v.x, v.y);
        pk.y = pk2(v.z, v.w);
        *reinterpret_cast<uint2*>(&A_lds[row * LDA + d]) = pk;
    }

    // prefetch first two B k-slices; latency overlaps the gather tail
    LOAD_B(b0, 0);
    LOAD_B(b1, 1);

    // hoist epilogue coefficients: bias + cost columns of W (L2 latency hides under GEMM)
    float bv[6], wc0[6], wc1[6];
    #pragma unroll
    for (int nf = 0; nf < 6; ++nf) {
        int col = wn * 96 + nf * 16 + l15;
        bool ok = col < DDIM;
        bv[nf]  = ok ? bias[col] : 0.f;
        wc0[nf] = ok ? W[col * DDIM + 320] : 0.f;
        wc1[nf] = ok ? W[col * DDIM + 321] : 0.f;
    }
    __syncthreads();

    // ---- MFMA GEMM: 4 waves as 1M x 4N, wave tile 64 x 96, reg-dbuf B, K=320 ----
    f32x4 acc[4][6];
    #pragma unroll
    for (int mf = 0; mf < 4; ++mf)
        #pragma unroll
        for (int nf = 0; nf < 6; ++nf)
            acc[mf][nf] = (f32x4){0.f, 0.f, 0.f, 0.f};

    const int arow0 = l15 * LDA + lq * 8;

#define GEMM_STEP(bank, ksl) {                                                   \
    bf16x8 a0 = *reinterpret_cast<const bf16x8*>(&A_lds[arow0 + (ksl) * 32]);    \
    bf16x8 a1 = *reinterpret_cast<const bf16x8*>(&A_lds[arow0 + 16 * LDA + (ksl) * 32]); \
    bf16x8 a2 = *reinterpret_cast<const bf16x8*>(&A_lds[arow0 + 32 * LDA + (ksl) * 32]); \
    bf16x8 a3 = *reinterpret_cast<const bf16x8*>(&A_lds[arow0 + 48 * LDA + (ksl) * 32]); \
    _Pragma("unroll")                                                            \
    for (int nf = 0; nf < 6; ++nf) {                                             \
        acc[0][nf] = __builtin_amdgcn_mfma_f32_16x16x32_bf16(a0, bank[nf], acc[0][nf], 0, 0, 0); \
        acc[1][nf] = __builtin_amdgcn_mfma_f32_16x16x32_bf16(a1, bank[nf], acc[1][nf], 0, 0, 0); \
        acc[2][nf] = __builtin_amdgcn_mfma_f32_16x16x32_bf16(a2, bank[nf], acc[2][nf], 0, 0, 0); \
        acc[3][nf] = __builtin_amdgcn_mfma_f32_16x16x32_bf16(a3, bank[nf], acc[3][nf], 0, 0, 0); \
    } }

    GEMM_STEP(b0, 0);
    #pragma unroll
    for (int kp = 0; kp < 4; ++kp) {
        LOAD_B(b0, 2 + 2 * kp);
        GEMM_STEP(b1, 1 + 2 * kp);
        LOAD_B(b1, 3 + 2 * kp);
        GEMM_STEP(b0, 2 + 2 * kp);
    }
    GEMM_STEP(b1, 9);

    // ---- epilogue: +bias +cost-rank2, leaky_relu; LDS transpose (2x32 rows) ----
    float* T_lds = reinterpret_cast<float*>(A_lds);         // 32*322*4 = 41.2 KB <= 45 KB
    float* outp = out + mbase * DDIM;
    const int CH4 = 32 * DDIM / 4;                          // 2576 f32x4 per 32-row chunk

    #pragma unroll
    for (int h = 0; h < 2; ++h) {
        __syncthreads();                                    // A_lds / prev chunk reads done
        #pragma unroll
        for (int m2 = 0; m2 < 2; ++m2) {
            const int mf = h * 2 + m2;
            #pragma unroll
            for (int r = 0; r < 4; ++r) {
                const int row  = m2 * 16 + lq * 4 + r;      // row within 32-chunk
                const int grow = h * 32 + row;              // row within block
                const float c0 = F_lds[grow * 12 + 10];
                const float c1 = F_lds[grow * 12 + 11];
                #pragma unroll
                for (int nf = 0; nf < 6; ++nf) {
                    int col = wn * 96 + nf * 16 + l15;
                    if (col < DDIM) {
                        float x = acc[mf][nf][r] + bv[nf] + c0 * wc0[nf] + c1 * wc1[nf];
                        x = (x > 0.f) ? x : 0.01f * x;
                        T_lds[row * DDIM + col] = x;
                    }
                }
            }
        }
        __syncthreads();
        #pragma unroll
        for (int i = 0; i < 11; ++i) {
            int fid = i * 256 + t;
            if (fid < CH4) {
                f32x4 v = *reinterpret_cast<const f32x4*>(&T_lds[fid * 4]);
                __builtin_nontemporal_store(v,
                    reinterpret_cast<f32x4*>(outp + ((long)h * CH4 + fid) * 4));
            }
        }
    }
}

extern "C" void kernel_launch(void* const* d_in, const int* in_sizes, int n_in,
                              void* d_out, int out_size, void* d_ws, size_t ws_size,
                              hipStream_t stream) {
    const float* feature      = (const float*)d_in[0];
    const float* join_tables  = (const float*)d_in[1];
    const float* type_embed   = (const float*)d_in[2];
    const float* column_embed = (const float*)d_in[3];
    const float* W            = (const float*)d_in[4];
    const float* bias         = (const float*)d_in[5];
    float* out = (float*)d_out;
    unsigned short* wb2 = (unsigned short*)d_ws;   // 11*24*512*2 = 270 KB

    hipLaunchKernelGGL(prep_w, dim3((NP * KP + 255) / 256), dim3(256), 0, stream, W, wb2);

    const int nblocks = (BTOT * SQLEN) / MBLK;    // 4096
    hipLaunchKernelGGL(fused_embed_gemm, dim3(nblocks), dim3(256), 0, stream,
                       feature, join_tables, type_embed, column_embed, wb2, W, bias, out);
}

// Round 20
// 128.896 us; speedup vs baseline: 1.2081x; 1.2081x over previous
//
#include <hip/hip_runtime.h>
#include <stdint.h>

#define BTOT 512
#define SQLEN 512
#define TTAB 20
#define EMB 32
#define DDIM 322            // E*10+2
#define KP 352              // padded K (11*32)
#define NP 384              // padded N (24*16) -> 6 frags per wave, 4 waves
#define MBLK 64             // rows per block
#define LDA 360             // A_lds row stride in bf16 elems (720B)
#define NFRAG 24            // total 16-wide N fragments

typedef __attribute__((ext_vector_type(4))) float f32x4;
typedef __attribute__((ext_vector_type(8))) __bf16 bf16x8;

// LDS-only barrier: drains lgkmcnt but NOT vmcnt -> nt stores stream across.
// Safe in epilogue: all cross-barrier deps there are LDS (T_lds / A_lds).
#define RAWBAR() asm volatile("s_waitcnt lgkmcnt(0)\n\ts_barrier" ::: "memory")

static __device__ __forceinline__ unsigned short f2bf(float f) {
    unsigned int u = __float_as_uint(f);
    u += 0x7fffu + ((u >> 16) & 1u);   // round-to-nearest-even
    return (unsigned short)(u >> 16);
}

// hardware RNE cvt pair-pack (v_cvt_pk_bf16_f32)
static __device__ __forceinline__ unsigned int pk2(float x, float y) {
    __bf16 a = (__bf16)x, b = (__bf16)y;
    unsigned short ua = __builtin_bit_cast(unsigned short, a);
    unsigned short ub = __builtin_bit_cast(unsigned short, b);
    return (unsigned int)ua | ((unsigned int)ub << 16);
}

// W [322][322] f32 (o x d) -> wb2 bf16 fragments in MFMA lane order.
// (n,k) -> frag ((k>>5)*24 + (n>>4)), lane ((n&15) | (((k>>3)&3)<<4)), e (k&7)
// A wave's B-fragment load = wb2 + frag*512 + lane*8 : contiguous 1KB.
__global__ void prep_w(const float* __restrict__ W, unsigned short* __restrict__ wb2) {
    int idx = blockIdx.x * 256 + threadIdx.x;
    if (idx >= NP * KP) return;
    int n = idx / KP;
    int k = idx - n * KP;
    float v = (n < DDIM && k < DDIM) ? W[n * DDIM + k] : 0.0f;
    int dst = ((k >> 5) * NFRAG + (n >> 4)) * 512
            + ((n & 15) + (((k >> 3) & 3) << 4)) * 8 + (k & 7);
    wb2[dst] = f2bf(v);
}

__global__ __launch_bounds__(256, 3) void fused_embed_gemm(
    const float* __restrict__ feature,       // [BT*SQ][12]
    const float* __restrict__ join_tables,   // [BT][20][32]
    const float* __restrict__ type_embed,    // [32][32]
    const float* __restrict__ column_embed,  // [300][32]
    const unsigned short* __restrict__ wb2,  // permuted bf16 W fragments
    const float* __restrict__ bias,          // [322]
    float* __restrict__ out)                 // [BT*SQ][322] f32
{
    __shared__ __align__(16) unsigned short A_lds[MBLK * LDA];  // 45 KB (reused by epilogue)
    __shared__ float F_lds[MBLK * 12];                          // 3 KB

    const int t = threadIdx.x;
    const long mbase = (long)blockIdx.x * MBLK;
    const int b = (int)(mbase >> 9);   // 64 | 512 => whole block in one batch

    const int lane = t & 63;
    const int wn   = t >> 6;          // wave owns frags wn*6 .. wn*6+5
    const int l15  = lane & 15;
    const int lq   = lane >> 4;
    const unsigned short* bbase = wb2 + ((long)(wn * 6) * 512) + lane * 8;

    bf16x8 b0[6], b1[6];

#define LOAD_B(bank, ksl)                                                        \
    _Pragma("unroll")                                                            \
    for (int nf = 0; nf < 6; ++nf)                                               \
        bank[nf] = *reinterpret_cast<const bf16x8*>(bbase + (long)((ksl) * NFRAG + nf) * 512);

    // ---- stage the 64 feature rows ----
    {
        const float* src = feature + mbase * 12;
        #pragma unroll
        for (int i = 0; i < 3; ++i) {
            int off = i * 256 + t;
            F_lds[off] = src[off];
        }
    }
    __syncthreads();

    // ---- gather embeddings into A_lds as bf16, float4 per iter ----
    const float* jtb = join_tables + (long)b * (TTAB * EMB);
    #pragma unroll 4
    for (int i = 0; i < 20; ++i) {              // 64 rows * 80 quads / 256 thr
        int pidx = i * 256 + t;
        int row = pidx / 80;
        int q = pidx - row * 80;
        int d = q << 2;
        int c = q >> 3;
        int j = d & 31;
        float4 v = make_float4(0.f, 0.f, 0.f, 0.f);
        int id = (int)F_lds[row * 12 + c];
        const float* src;
        bool nz = true;
        if (c == 0)                            { src = type_embed + id * EMB;  nz = (id != 0); }
        else if (c == 1 || (c >= 4 && c <= 6)) { src = jtb + id * EMB; }
        else                                   { src = column_embed + id * EMB; nz = (id != 0); }
        if (nz) v = *reinterpret_cast<const float4*>(src + j);
        uint2 pk;
        pk.x = pk2(v.x, v.y);
        pk.y = pk2(v.z, v.w);
        *reinterpret_cast<uint2*>(&A_lds[row * LDA + d]) = pk;
    }
    // ---- cost pair + zero pad: d in [320,360) ----
    #pragma unroll
    for (int i = 0; i < 3; ++i) {
        int pidx = i * 256 + t;
        if (pidx < 640) {
            int row = pidx / 10;
            int gi = pidx - row * 10;
            int d = 320 + (gi << 2);
            uint2 pk = make_uint2(0u, 0u);
            if (gi == 0) {
                pk.x = pk2(F_lds[row * 12 + 10], F_lds[row * 12 + 11]);
            }
            *reinterpret_cast<uint2*>(&A_lds[row * LDA + d]) = pk;
        }
    }

    // prefetch first two B k-slices; latency overlaps the gather tail
    LOAD_B(b0, 0);
    LOAD_B(b1, 1);
    __syncthreads();

    // ---- MFMA GEMM: 4 waves as 1M x 4N, wave tile 64 x 96, reg-dbuf B ----
    f32x4 acc[4][6];
    #pragma unroll
    for (int mf = 0; mf < 4; ++mf)
        #pragma unroll
        for (int nf = 0; nf < 6; ++nf)
            acc[mf][nf] = (f32x4){0.f, 0.f, 0.f, 0.f};

    const int arow0 = l15 * LDA + lq * 8;

#define GEMM_STEP(bank, ksl) {                                                   \
    bf16x8 a0 = *reinterpret_cast<const bf16x8*>(&A_lds[arow0 + (ksl) * 32]);    \
    bf16x8 a1 = *reinterpret_cast<const bf16x8*>(&A_lds[arow0 + 16 * LDA + (ksl) * 32]); \
    bf16x8 a2 = *reinterpret_cast<const bf16x8*>(&A_lds[arow0 + 32 * LDA + (ksl) * 32]); \
    bf16x8 a3 = *reinterpret_cast<const bf16x8*>(&A_lds[arow0 + 48 * LDA + (ksl) * 32]); \
    _Pragma("unroll")                                                            \
    for (int nf = 0; nf < 6; ++nf) {                                             \
        acc[0][nf] = __builtin_amdgcn_mfma_f32_16x16x32_bf16(a0, bank[nf], acc[0][nf], 0, 0, 0); \
        acc[1][nf] = __builtin_amdgcn_mfma_f32_16x16x32_bf16(a1, bank[nf], acc[1][nf], 0, 0, 0); \
        acc[2][nf] = __builtin_amdgcn_mfma_f32_16x16x32_bf16(a2, bank[nf], acc[2][nf], 0, 0, 0); \
        acc[3][nf] = __builtin_amdgcn_mfma_f32_16x16x32_bf16(a3, bank[nf], acc[3][nf], 0, 0, 0); \
    } }

    GEMM_STEP(b0, 0);
    #pragma unroll
    for (int kp = 0; kp < 4; ++kp) {
        LOAD_B(b0, 2 + 2 * kp);
        GEMM_STEP(b1, 1 + 2 * kp);
        LOAD_B(b1, 3 + 2 * kp);
        GEMM_STEP(b0, 2 + 2 * kp);
    }
    LOAD_B(b0, 10);
    GEMM_STEP(b1, 9);
    GEMM_STEP(b0, 10);

    // ---- epilogue: +bias, leaky_relu; LDS transpose (2 chunks of 32 rows) ----
    // RAWBAR (lgkm-only): chunk-0 nt stores stay in flight through chunk 1.
    float bv[6];
    #pragma unroll
    for (int nf = 0; nf < 6; ++nf) {
        int col = wn * 96 + nf * 16 + l15;
        bv[nf] = (col < DDIM) ? bias[col] : 0.f;
    }

    float* T_lds = reinterpret_cast<float*>(A_lds);         // 32*322*4 = 41.2 KB <= 45 KB
    float* outp = out + mbase * DDIM;
    const int CH4 = 32 * DDIM / 4;                          // 2576 f32x4 per 32-row chunk

    #pragma unroll
    for (int h = 0; h < 2; ++h) {
        RAWBAR();                                           // A_lds / prev chunk reads done
        #pragma unroll
        for (int m2 = 0; m2 < 2; ++m2) {
            const int mf = h * 2 + m2;
            #pragma unroll
            for (int nf = 0; nf < 6; ++nf) {
                int col = wn * 96 + nf * 16 + l15;
                if (col < DDIM) {
                    #pragma unroll
                    for (int r = 0; r < 4; ++r) {
                        float x = acc[mf][nf][r] + bv[nf];
                        x = (x > 0.f) ? x : 0.01f * x;
                        T_lds[(m2 * 16 + lq * 4 + r) * DDIM + col] = x;
                    }
                }
            }
        }
        RAWBAR();                                           // T writes visible
        #pragma unroll
        for (int i = 0; i < 11; ++i) {
            int fid = i * 256 + t;
            if (fid < CH4) {
                f32x4 v = *reinterpret_cast<const f32x4*>(&T_lds[fid * 4]);
                __builtin_nontemporal_store(v,
                    reinterpret_cast<f32x4*>(outp + ((long)h * CH4 + fid) * 4));
            }
        }
    }
}

extern "C" void kernel_launch(void* const* d_in, const int* in_sizes, int n_in,
                              void* d_out, int out_size, void* d_ws, size_t ws_size,
                              hipStream_t stream) {
    const float* feature      = (const float*)d_in[0];
    const float* join_tables  = (const float*)d_in[1];
    const float* type_embed   = (const float*)d_in[2];
    const float* column_embed = (const float*)d_in[3];
    const float* W            = (const float*)d_in[4];
    const float* bias         = (const float*)d_in[5];
    float* out = (float*)d_out;
    unsigned short* wb2 = (unsigned short*)d_ws;   // 11*24*512*2 = 270 KB

    hipLaunchKernelGGL(prep_w, dim3((NP * KP + 255) / 256), dim3(256), 0, stream, W, wb2);

    const int nblocks = (BTOT * SQLEN) / MBLK;    // 4096
    hipLaunchKernelGGL(fused_embed_gemm, dim3(nblocks), dim3(256), 0, stream,
                       feature, join_tables, type_embed, column_embed, wb2, bias, out);
}